// Round 6
// baseline (326.419 us; speedup 1.0000x reference)
//
#include <hip/hip_runtime.h>

#define LSEQ 2048
#define EMB  512
#define NH   8
#define HD   64
#define NBATCH 4
// 1/sqrt(512) * log2(e): folded into Q projection; softmax runs in exp2 domain
#define QSCALE (0.044194173824159216f * 1.4426950408889634f)

using short8  = __attribute__((ext_vector_type(8))) short;
using short4v = __attribute__((ext_vector_type(4))) short;
using f32x4   = __attribute__((ext_vector_type(4))) float;

__device__ __forceinline__ short bf16r(float f) {
  union { float f; unsigned u; } x; x.f = f;
  unsigned r = x.u + 0x7FFFu + ((x.u >> 16) & 1u);
  return (short)(r >> 16);
}

__device__ __forceinline__ float exp2v(float x) {
  float r;
  asm("v_exp_f32 %0, %1" : "=v"(r) : "v"(x));   // D = 2^S0
  return r;
}

// pack two f32 -> two bf16 in one dword (lo -> [15:0], hi -> [31:16])
__device__ __forceinline__ unsigned cvtpk(float lo, float hi) {
  unsigned r;
  asm("v_cvt_pk_bf16_f32 %0, %1, %2" : "=v"(r) : "v"(lo), "v"(hi));
  return r;
}

__device__ __forceinline__ short8 cvt8(const float* __restrict__ p) {
  float4 a = ((const float4*)p)[0];
  float4 b = ((const float4*)p)[1];
  short8 r;
  r[0]=bf16r(a.x); r[1]=bf16r(a.y); r[2]=bf16r(a.z); r[3]=bf16r(a.w);
  r[4]=bf16r(b.x); r[5]=bf16r(b.y); r[6]=bf16r(b.z); r[7]=bf16r(b.w);
  return r;
}

__device__ __forceinline__ short8 ld8(const short* __restrict__ p) {
  return *(const short8*)p;
}

// ---------------------------------------------------------------- Wo -> bf16
__global__ __launch_bounds__(256) void cvt_wo(const float* __restrict__ Wo,
                                              short* __restrict__ Wob) {
  int i = blockIdx.x * 256 + threadIdx.x;
  float4 v = ((const float4*)Wo)[i];
  short4v r;
  r[0]=bf16r(v.x); r[1]=bf16r(v.y); r[2]=bf16r(v.z); r[3]=bf16r(v.w);
  ((short4v*)Wob)[i] = r;
}

// ------------------------------------------------- mask -> additive f32 bias
__global__ __launch_bounds__(256) void mask2bias(const int* __restrict__ mask,
                                                 float* __restrict__ fbias) {
  int i = blockIdx.x * 256 + threadIdx.x;   // 32 blocks * 256 = 8192
  fbias[i] = mask[i] ? 0.f : -1e30f;
}

// ------------------------------------------------- per-head QKV projections
__global__ __launch_bounds__(256) void proj_kernel(
    const float* __restrict__ query, const float* __restrict__ keys,
    const float* __restrict__ values,
    const float* __restrict__ Wq, const float* __restrict__ Wk,
    const float* __restrict__ Wv,
    short* __restrict__ Qp, short* __restrict__ Kp, short* __restrict__ Vt) {
  int t = blockIdx.y;
  const float* x = (t == 0) ? query : (t == 1) ? keys : values;
  const float* W = (t == 0) ? Wq    : (t == 1) ? Wk   : Wv;
  int idx = blockIdx.x;
  int lt = idx & 31, h = (idx >> 5) & 7, n = idx >> 8;
  int tid = threadIdx.x, lane = tid & 63, w = tid >> 6;
  int row16 = lane & 15, g = lane >> 4;
  int lbase = lt * 64 + w * 16;

  const float* xr = x + ((size_t)(n * LSEQ + lbase + row16)) * EMB + h * HD + g * 8;
  short8 a0 = cvt8(xr);
  short8 a1 = cvt8(xr + 32);

  f32x4 acc[4];
#pragma unroll
  for (int et = 0; et < 4; et++) acc[et] = (f32x4){0.f, 0.f, 0.f, 0.f};
#pragma unroll
  for (int et = 0; et < 4; et++) {
    const float* wr = W + (size_t)(et * 16 + row16) * HD + g * 8;
    short8 b0 = cvt8(wr);
    short8 b1 = cvt8(wr + 32);
    acc[et] = __builtin_amdgcn_mfma_f32_16x16x32_bf16(a0, b0, acc[et], 0, 0, 0);
    acc[et] = __builtin_amdgcn_mfma_f32_16x16x32_bf16(a1, b1, acc[et], 0, 0, 0);
  }

  float sc = (t == 0) ? QSCALE : 1.f;
  if (t == 2) {  // V transposed: Vt[n][h][d][L]
#pragma unroll
    for (int et = 0; et < 4; et++)
#pragma unroll
      for (int r = 0; r < 4; r++) {
        int d = et * 16 + row16;
        int l = lbase + g * 4 + r;
        Vt[((size_t)((n * NH + h) * HD + d)) * LSEQ + l] = bf16r(acc[et][r]);
      }
  } else {
    short* O = (t == 0) ? Qp : Kp;
#pragma unroll
    for (int et = 0; et < 4; et++)
#pragma unroll
      for (int r = 0; r < 4; r++) {
        int l = lbase + g * 4 + r;
        O[((size_t)((n * NH + h) * LSEQ + l)) * HD + et * 16 + row16] =
            bf16r(acc[et][r] * sc);
      }
  }
}

// ------------------------------------------------------------ flash attention
// block = (n, h, qtile of 16); 4 waves split-K (wave w owns keys [w*512,...)).
// SWAPPED QK^T: mfma(K_frag, Q_frag) -> S^T: lane (q0=lane&15, g=lane>>4)
// holds S[k = 16ks+4g+r][q0]. Row-softmax is in-lane over 16 values + 2
// shfl_xor for the max; lsum reduced once after the loop. P packed via
// cvt_pk_bf16 -> 4 ds_write_b64 + 2 ds_read_b128 per iter (bit-6 XOR swizzle).
union AttnSmem {
  short P[4][16][72];                       // 9216 B, swizzled columns
  struct {
    float acc[4][16][68];                   // merge: per-wave O partials
    float ml[4][2][16];                     // [w][0]=m, [w][1]=l per q-row
  } mg;
};

__global__ __launch_bounds__(256) void attn_kernel(
    const short* __restrict__ Qp, const short* __restrict__ Kp,
    const short* __restrict__ Vt, const float* __restrict__ fbias,
    short* __restrict__ aout) {
  __shared__ AttnSmem sm;

  int idx = blockIdx.x;
  int qt = idx & 127, h = (idx >> 7) & 7, n = idx >> 10;
  int tid = threadIdx.x, lane = tid & 63, w = tid >> 6;
  int q0 = lane & 15, g = lane >> 4;

  size_t nh = (size_t)(n * NH + h);
  // Q as B-fragment: lane holds Q[q0][g*8..g*8+7] per K=32 half
  const short* Qb = Qp + (nh * LSEQ + qt * 16) * HD;
  short8 bq0 = ld8(Qb + q0 * HD + g * 8);
  short8 bq1 = ld8(Qb + q0 * HD + 32 + g * 8);

  f32x4 acc[4];
#pragma unroll
  for (int dt = 0; dt < 4; dt++) acc[dt] = (f32x4){0.f, 0.f, 0.f, 0.f};
  float m = -3e38f, lsum = 0.f;

  // base pointers (lane-invariant parts folded once)
  const short* Kbase = Kp + nh * LSEQ * HD + (size_t)(w * 512 + q0) * HD + g * 8;
  const short* Vbase = Vt + nh * HD * LSEQ + (size_t)q0 * LSEQ + w * 512 + g * 8;
  const float* fb    = fbias + n * LSEQ + w * 512 + g * 4;

  // precomputed swizzled LDS pointers (loop-invariant)
  char* Prow = (char*)&sm.P[w][q0][0];
  int sw = (q0 & 1) << 6;                       // byte XOR: spread read banks
  char* wr0 = Prow + ((0  + 8 * g) ^ sw);
  char* wr1 = Prow + ((32 + 8 * g) ^ sw);
  char* wr2 = Prow + ((64 + 8 * g) ^ sw);
  char* wr3 = Prow + ((96 + 8 * g) ^ sw);
  const char* rd0 = Prow + ((16 * g) ^ sw);
  const char* rd1 = Prow + ((64 + 16 * g) ^ sw);

  for (int kt = 0; kt < 8; kt++) {
    int kb = kt * 64;
    short8 kf0[4], kf1[4], vf0[4], vf1[4];
#pragma unroll
    for (int ks = 0; ks < 4; ks++) {
      const short* Kb = Kbase + (size_t)(kb + ks * 16) * HD;
      kf0[ks] = ld8(Kb);
      kf1[ks] = ld8(Kb + 32);
    }
#pragma unroll
    for (int dt = 0; dt < 4; dt++) {
      const short* Vb = Vbase + (size_t)(dt * 16) * LSEQ + kb;
      vf0[dt] = ld8(Vb);
      vf1[dt] = ld8(Vb + 32);
    }
    f32x4 fbv[4];
#pragma unroll
    for (int ks = 0; ks < 4; ks++)
      fbv[ks] = *(const f32x4*)(fb + kb + ks * 16);

    // ---- S^T = K Q^T : lane holds s[ks][r] = S[k=16ks+4g+r][q0] + bias
    f32x4 s[4];
    __builtin_amdgcn_s_setprio(1);
#pragma unroll
    for (int ks = 0; ks < 4; ks++) {
      f32x4 t = (f32x4){0.f, 0.f, 0.f, 0.f};
      t = __builtin_amdgcn_mfma_f32_16x16x32_bf16(kf0[ks], bq0, t, 0, 0, 0);
      t = __builtin_amdgcn_mfma_f32_16x16x32_bf16(kf1[ks], bq1, t, 0, 0, 0);
      s[ks] = t + fbv[ks];
    }
    __builtin_amdgcn_s_setprio(0);

    // ---- in-lane max over 16, then across the 4 g-groups (2 shuffles)
    float t01 = fmaxf(fmaxf(s[0][0], s[0][1]), fmaxf(s[0][2], s[0][3]));
    float t1  = fmaxf(fmaxf(s[1][0], s[1][1]), fmaxf(s[1][2], s[1][3]));
    float t2  = fmaxf(fmaxf(s[2][0], s[2][1]), fmaxf(s[2][2], s[2][3]));
    float t3  = fmaxf(fmaxf(s[3][0], s[3][1]), fmaxf(s[3][2], s[3][3]));
    float tmax = fmaxf(fmaxf(t01, t1), fmaxf(t2, t3));
    tmax = fmaxf(tmax, __shfl_xor(tmax, 16));
    tmax = fmaxf(tmax, __shfl_xor(tmax, 32));

    // ---- defer-max rescale (T13)
    if (__any(tmax > m + 8.f)) {
      float mn = fmaxf(m, tmax);
      float sf = exp2v(m - mn);
      lsum *= sf;
      m = mn;
      int lb = lane & 48;
      float sfr[4];
#pragma unroll
      for (int r = 0; r < 4; r++) sfr[r] = __shfl(sf, lb + g * 4 + r);
#pragma unroll
      for (int dt = 0; dt < 4; dt++)
#pragma unroll
        for (int r = 0; r < 4; r++) acc[dt][r] *= sfr[r];
    }

    // ---- p = exp2(s - m); pack pairs to bf16; 4x ds_write_b64
    float ps = 0.f;
#pragma unroll
    for (int ks = 0; ks < 4; ks++) {
      float p0 = exp2v(s[ks][0] - m);
      float p1 = exp2v(s[ks][1] - m);
      float p2 = exp2v(s[ks][2] - m);
      float p3 = exp2v(s[ks][3] - m);
      ps += (p0 + p1) + (p2 + p3);
      int2 pk = make_int2((int)cvtpk(p0, p1), (int)cvtpk(p2, p3));
      char* wp = (ks == 0) ? wr0 : (ks == 1) ? wr1 : (ks == 2) ? wr2 : wr3;
      *(int2*)wp = pk;
    }
    lsum += ps;          // per-lane partial (its own 16 k's); reduced later

    // ---- O += P V
    short8 ap0 = *(const short8*)rd0;
    short8 ap1 = *(const short8*)rd1;
    __builtin_amdgcn_s_setprio(1);
#pragma unroll
    for (int dt = 0; dt < 4; dt++) {
      acc[dt] = __builtin_amdgcn_mfma_f32_16x16x32_bf16(ap0, vf0[dt], acc[dt], 0, 0, 0);
      acc[dt] = __builtin_amdgcn_mfma_f32_16x16x32_bf16(ap1, vf1[dt], acc[dt], 0, 0, 0);
    }
    __builtin_amdgcn_s_setprio(0);
  }

  // deferred lsum reduction across the 4 g-lanes of each q0
  lsum += __shfl_xor(lsum, 16);
  lsum += __shfl_xor(lsum, 32);

  // ---- merge the 4 waves' partial (m, l, acc) --------------------------
  __syncthreads();                     // all waves done with sm.P
#pragma unroll
  for (int dt = 0; dt < 4; dt++)
#pragma unroll
    for (int r = 0; r < 4; r++)
      sm.mg.acc[w][g * 4 + r][dt * 16 + q0] = acc[dt][r];
  if (g == 0) {
    sm.mg.ml[w][0][q0] = m;
    sm.mg.ml[w][1][q0] = lsum;
  }
  __syncthreads();

  // wave w combines rows [w*4, w*4+4): lane -> row = w*4 + (lane>>4)
  int row = w * 4 + (lane >> 4);
  float mw[4], lw[4];
#pragma unroll
  for (int wv = 0; wv < 4; wv++) {
    mw[wv] = sm.mg.ml[wv][0][row];
    lw[wv] = sm.mg.ml[wv][1][row];
  }
  float M = fmaxf(fmaxf(mw[0], mw[1]), fmaxf(mw[2], mw[3]));
  float sf[4], L = 0.f;
#pragma unroll
  for (int wv = 0; wv < 4; wv++) {
    sf[wv] = exp2v(mw[wv] - M);
    L += sf[wv] * lw[wv];
  }
  float inv = L > 0.f ? 1.f / L : 0.f;
  int q = qt * 16 + row;
#pragma unroll
  for (int j = 0; j < 4; j++) {
    int col = j * 16 + q0;
    float o = sf[0] * sm.mg.acc[0][row][col] + sf[1] * sm.mg.acc[1][row][col] +
              sf[2] * sm.mg.acc[2][row][col] + sf[3] * sm.mg.acc[3][row][col];
    aout[((size_t)(n * LSEQ + q)) * EMB + h * HD + col] = bf16r(o * inv);
  }
}

// --------------------------------------------------- final projection + bias
__global__ __launch_bounds__(256) void outproj_kernel(
    const short* __restrict__ aout, const short* __restrict__ Wob,
    const float* __restrict__ bo, float* __restrict__ out) {
  int mt = blockIdx.x, nt = blockIdx.y;
  int tid = threadIdx.x, lane = tid & 63, w = tid >> 6;
  int row16 = lane & 15, g = lane >> 4;
  int mrow = mt * 64 + w * 16;

  f32x4 acc[4];
#pragma unroll
  for (int et = 0; et < 4; et++) acc[et] = (f32x4){0.f, 0.f, 0.f, 0.f};

  for (int kc = 0; kc < 16; kc++) {
    short8 a = ld8(aout + (size_t)(mrow + row16) * EMB + kc * 32 + g * 8);
#pragma unroll
    for (int et = 0; et < 4; et++) {
      short8 b = ld8(Wob + (size_t)(nt * 64 + et * 16 + row16) * EMB + kc * 32 + g * 8);
      acc[et] = __builtin_amdgcn_mfma_f32_16x16x32_bf16(a, b, acc[et], 0, 0, 0);
    }
  }
#pragma unroll
  for (int et = 0; et < 4; et++) {
    int e = nt * 64 + et * 16 + row16;
    float bias = bo[e];
#pragma unroll
    for (int r = 0; r < 4; r++) {
      int row = mrow + g * 4 + r;
      out[(size_t)row * EMB + e] = acc[et][r] + bias;
    }
  }
}

extern "C" void kernel_launch(void* const* d_in, const int* in_sizes, int n_in,
                              void* d_out, int out_size, void* d_ws, size_t ws_size,
                              hipStream_t stream) {
  const float* values = (const float*)d_in[0];
  const float* keys   = (const float*)d_in[1];
  const float* query  = (const float*)d_in[2];
  const int*   mask   = (const int*)d_in[3];
  const float* Wv     = (const float*)d_in[4];
  const float* Wk     = (const float*)d_in[5];
  const float* Wq     = (const float*)d_in[6];
  const float* Wo     = (const float*)d_in[7];
  const float* bo     = (const float*)d_in[8];
  float* out = (float*)d_out;

  // Qp/Kp scratch in d_out (16 MB, overwritten by outproj last; stream-ordered)
  short* Qp = (short*)d_out;
  short* Kp = (short*)((char*)d_out + (8u << 20));
  char* ws = (char*)d_ws;
  short* Vt    = (short*)(ws);                            //  8 MB
  short* aout  = (short*)(ws + (8u << 20));               //  8 MB
  short* Wob   = (short*)(ws + (16u << 20));              // 0.5 MB
  float* fbias = (float*)(ws + (16u << 20) + (512u << 10)); // 32 KB

  cvt_wo<<<256, 256, 0, stream>>>(Wo, Wob);
  mask2bias<<<32, 256, 0, stream>>>(mask, fbias);
  proj_kernel<<<dim3(NBATCH * NH * (LSEQ / 64), 3), 256, 0, stream>>>(
      query, keys, values, Wq, Wk, Wv, Qp, Kp, Vt);
  attn_kernel<<<NBATCH * NH * (LSEQ / 16), 256, 0, stream>>>(Qp, Kp, Vt, fbias, aout);
  outproj_kernel<<<dim3((NBATCH * LSEQ) / 64, EMB / 64), 256, 0, stream>>>(
      aout, Wob, bo, out);
}

// Round 7
// 141.692 us; speedup vs baseline: 2.3037x; 2.3037x over previous
//
#include <hip/hip_runtime.h>

#define LSEQ 2048
#define EMB  512
#define NH   8
#define HD   64
#define NBATCH 4
// 1/sqrt(512) * log2(e): folded into Q projection; softmax runs in exp2 domain
#define QSCALE (0.044194173824159216f * 1.4426950408889634f)

using short8  = __attribute__((ext_vector_type(8))) short;
using short4v = __attribute__((ext_vector_type(4))) short;
using f32x4   = __attribute__((ext_vector_type(4))) float;

__device__ __forceinline__ short bf16r(float f) {
  union { float f; unsigned u; } x; x.f = f;
  unsigned r = x.u + 0x7FFFu + ((x.u >> 16) & 1u);
  return (short)(r >> 16);
}

__device__ __forceinline__ float exp2v(float x) {
  float r;
  asm("v_exp_f32 %0, %1" : "=v"(r) : "v"(x));   // D = 2^S0
  return r;
}

// pack two f32 -> two bf16 in one dword (lo -> [15:0], hi -> [31:16])
__device__ __forceinline__ unsigned cvtpk(float lo, float hi) {
  unsigned r;
  asm("v_cvt_pk_bf16_f32 %0, %1, %2" : "=v"(r) : "v"(lo), "v"(hi));
  return r;
}

// async global->LDS, 16B per lane; ldst must be wave-uniform (HW adds lane*16)
__device__ __forceinline__ void stage16(const void* g, void* l) {
  __builtin_amdgcn_global_load_lds(
      (const __attribute__((address_space(1))) unsigned int*)g,
      (__attribute__((address_space(3))) unsigned int*)l, 16, 0, 0);
}

__device__ __forceinline__ short8 cvt8(const float* __restrict__ p) {
  float4 a = ((const float4*)p)[0];
  float4 b = ((const float4*)p)[1];
  short8 r;
  r[0]=bf16r(a.x); r[1]=bf16r(a.y); r[2]=bf16r(a.z); r[3]=bf16r(a.w);
  r[4]=bf16r(b.x); r[5]=bf16r(b.y); r[6]=bf16r(b.z); r[7]=bf16r(b.w);
  return r;
}

__device__ __forceinline__ short8 ld8(const short* __restrict__ p) {
  return *(const short8*)p;
}

// ---------------------------------------------------------------- Wo -> bf16
__global__ __launch_bounds__(256) void cvt_wo(const float* __restrict__ Wo,
                                              short* __restrict__ Wob) {
  int i = blockIdx.x * 256 + threadIdx.x;
  float4 v = ((const float4*)Wo)[i];
  short4v r;
  r[0]=bf16r(v.x); r[1]=bf16r(v.y); r[2]=bf16r(v.z); r[3]=bf16r(v.w);
  ((short4v*)Wob)[i] = r;
}

// ------------------------------------------------- mask -> additive f32 bias
__global__ __launch_bounds__(256) void mask2bias(const int* __restrict__ mask,
                                                 float* __restrict__ fbias) {
  int i = blockIdx.x * 256 + threadIdx.x;   // 32 blocks * 256 = 8192
  fbias[i] = mask[i] ? 0.f : -1e30f;
}

// ------------------------------------------------- per-head QKV projections
__global__ __launch_bounds__(256) void proj_kernel(
    const float* __restrict__ query, const float* __restrict__ keys,
    const float* __restrict__ values,
    const float* __restrict__ Wq, const float* __restrict__ Wk,
    const float* __restrict__ Wv,
    short* __restrict__ Qp, short* __restrict__ Kp, short* __restrict__ Vt) {
  int t = blockIdx.y;
  const float* x = (t == 0) ? query : (t == 1) ? keys : values;
  const float* W = (t == 0) ? Wq    : (t == 1) ? Wk   : Wv;
  int idx = blockIdx.x;
  int lt = idx & 31, h = (idx >> 5) & 7, n = idx >> 8;
  int tid = threadIdx.x, lane = tid & 63, w = tid >> 6;
  int row16 = lane & 15, g = lane >> 4;
  int lbase = lt * 64 + w * 16;

  const float* xr = x + ((size_t)(n * LSEQ + lbase + row16)) * EMB + h * HD + g * 8;
  short8 a0 = cvt8(xr);
  short8 a1 = cvt8(xr + 32);

  f32x4 acc[4];
#pragma unroll
  for (int et = 0; et < 4; et++) acc[et] = (f32x4){0.f, 0.f, 0.f, 0.f};
#pragma unroll
  for (int et = 0; et < 4; et++) {
    const float* wr = W + (size_t)(et * 16 + row16) * HD + g * 8;
    short8 b0 = cvt8(wr);
    short8 b1 = cvt8(wr + 32);
    acc[et] = __builtin_amdgcn_mfma_f32_16x16x32_bf16(a0, b0, acc[et], 0, 0, 0);
    acc[et] = __builtin_amdgcn_mfma_f32_16x16x32_bf16(a1, b1, acc[et], 0, 0, 0);
  }

  float sc = (t == 0) ? QSCALE : 1.f;
  if (t == 2) {  // V transposed: Vt[n][h][d][L]
#pragma unroll
    for (int et = 0; et < 4; et++)
#pragma unroll
      for (int r = 0; r < 4; r++) {
        int d = et * 16 + row16;
        int l = lbase + g * 4 + r;
        Vt[((size_t)((n * NH + h) * HD + d)) * LSEQ + l] = bf16r(acc[et][r]);
      }
  } else {
    short* O = (t == 0) ? Qp : Kp;
#pragma unroll
    for (int et = 0; et < 4; et++)
#pragma unroll
      for (int r = 0; r < 4; r++) {
        int l = lbase + g * 4 + r;
        O[((size_t)((n * NH + h) * LSEQ + l)) * HD + et * 16 + row16] =
            bf16r(acc[et][r] * sc);
      }
  }
}

// ------------------------------------------------------------ flash attention
// block = (n, h, qtile of 64); 4 waves each own 16 q-rows, SHARE the K/V tile.
// K/V (64 keys) staged to LDS via async global_load_lds, double-buffered,
// chunk-XOR swizzled (col^=row&7 at 16B granularity, applied at the global
// SOURCE; read applies the same XOR -> conflict-free ds_read_b128).
// Swapped QK^T (softmax in-lane, exp2 domain), P through per-wave LDS.
// LDS: K0[0,8K) K1[8K,16K) V0[16K,24K) V1[24K,32K) P[32K,40K) = 40960 B
// -> exactly 4 blocks/CU; __launch_bounds__(256,4) caps VGPR at 128.
__global__ __launch_bounds__(256, 4) void attn_kernel(
    const short* __restrict__ Qp, const short* __restrict__ Kp,
    const short* __restrict__ Vt, const float* __restrict__ fbias,
    short* __restrict__ aout) {
  __shared__ __align__(16) char smem[40960];

  int idx = blockIdx.x;
  int qt = idx & 31, h = (idx >> 5) & 7, n = idx >> 8;
  int tid = threadIdx.x, lane = tid & 63, w = tid >> 6;
  int q0 = lane & 15, g = lane >> 4;
  int xr = q0 & 7;

  size_t nh = (size_t)(n * NH + h);
  // Q as B-fragment: lane holds Q[q0][g*8..] per K=32 half
  const short* Qb = Qp + (nh * LSEQ + qt * 64 + w * 16) * HD;
  short8 bq0 = ld8(Qb + q0 * HD + g * 8);
  short8 bq1 = ld8(Qb + q0 * HD + 32 + g * 8);

  f32x4 acc[4];
#pragma unroll
  for (int dt = 0; dt < 4; dt++) acc[dt] = (f32x4){0.f, 0.f, 0.f, 0.f};
  float m = -3e38f, lsum = 0.f;

  const char* Ksrc = (const char*)(Kp + nh * (size_t)LSEQ * HD);  // [l][d] rows 128B
  const char* Vsrc = (const char*)(Vt + nh * (size_t)HD * LSEQ);  // [d][L] rows 4KB
  const float* fb  = fbias + n * LSEQ + g * 4;

  // staging geometry: K/V tile = 64 rows x 128B = 512 chunks of 16B;
  // thread covers chunks c=w*64+lane and c+256; source col-chunk ^= row&7.
  int c0 = w * 64 + lane, r0 = c0 >> 3, col0 = (c0 & 7) ^ (r0 & 7);
  int c1 = c0 + 256,      r1 = c1 >> 3, col1 = (c1 & 7) ^ (r1 & 7);
  int ksoff0 = r0 * 128 + col0 * 16;
  int ksoff1 = r1 * 128 + col1 * 16;
  int vsoff0 = r0 * (LSEQ * 2) + col0 * 16;
  int vsoff1 = r1 * (LSEQ * 2) + col1 * 16;
  int ldoff0 = (w * 64) * 16;           // + lane*16 added by HW
  int ldoff1 = ldoff0 + 256 * 16;

  // swizzled read offsets (within a K/V tile): row q0-based, chunk g ^ xr
  int kfrag = q0 * 128 + ((g ^ xr) << 4);        // + ks*2048; half1 = ^64
  // P region: per-wave [16 rows][128B], XOR (xr<<4) per row
  int pbase = 32768 + w * 2048 + q0 * 128;
  char* pw[4];
#pragma unroll
  for (int ks = 0; ks < 4; ks++)
    pw[ks] = smem + pbase + ((ks * 32 + g * 8) ^ (xr << 4));
  const char* pr0 = smem + pbase + ((g * 16) ^ (xr << 4));
  const char* pr1 = smem + pbase + ((64 + g * 16) ^ (xr << 4));

  // prologue: stage k-block 0 into buf0
  stage16(Ksrc + ksoff0, smem + ldoff0);
  stage16(Ksrc + ksoff1, smem + ldoff1);
  stage16(Vsrc + vsoff0, smem + 16384 + ldoff0);
  stage16(Vsrc + vsoff1, smem + 16384 + ldoff1);
  __syncthreads();

  for (int kt = 0; kt < 32; kt++) {
    int buf = kt & 1;
    // ---- issue next tile's async staging (hidden under this iter's compute)
    if (kt < 31) {
      int nkb = (kt + 1) * 64;
      int bo = (buf ^ 1) * 8192;
      stage16(Ksrc + nkb * 128 + ksoff0, smem + bo + ldoff0);
      stage16(Ksrc + nkb * 128 + ksoff1, smem + bo + ldoff1);
      stage16(Vsrc + nkb * 2 + vsoff0, smem + 16384 + bo + ldoff0);
      stage16(Vsrc + nkb * 2 + vsoff1, smem + 16384 + bo + ldoff1);
    }
    f32x4 fbv[4];
#pragma unroll
    for (int ks = 0; ks < 4; ks++)
      fbv[ks] = *(const f32x4*)(fb + kt * 64 + ks * 16);

    // ---- S^T = K Q^T from LDS; lane holds s[ks][r] = S[k=16ks+4g+r][q0]
    int kb_l = buf * 8192 + kfrag;
    f32x4 s[4];
    __builtin_amdgcn_s_setprio(1);
#pragma unroll
    for (int ks = 0; ks < 4; ks++) {
      short8 k0 = *(const short8*)(smem + (kb_l + ks * 2048));
      short8 k1 = *(const short8*)(smem + ((kb_l + ks * 2048) ^ 64));
      f32x4 t = (f32x4){0.f, 0.f, 0.f, 0.f};
      t = __builtin_amdgcn_mfma_f32_16x16x32_bf16(k0, bq0, t, 0, 0, 0);
      t = __builtin_amdgcn_mfma_f32_16x16x32_bf16(k1, bq1, t, 0, 0, 0);
      s[ks] = t + fbv[ks];
    }
    __builtin_amdgcn_s_setprio(0);

    // ---- in-lane max over 16 k's, then across the 4 g-groups (2 shuffles)
    float t0 = fmaxf(fmaxf(s[0][0], s[0][1]), fmaxf(s[0][2], s[0][3]));
    float t1 = fmaxf(fmaxf(s[1][0], s[1][1]), fmaxf(s[1][2], s[1][3]));
    float t2 = fmaxf(fmaxf(s[2][0], s[2][1]), fmaxf(s[2][2], s[2][3]));
    float t3 = fmaxf(fmaxf(s[3][0], s[3][1]), fmaxf(s[3][2], s[3][3]));
    float tmax = fmaxf(fmaxf(t0, t1), fmaxf(t2, t3));
    tmax = fmaxf(tmax, __shfl_xor(tmax, 16));
    tmax = fmaxf(tmax, __shfl_xor(tmax, 32));

    // ---- defer-max rescale (T13); taken on first iter since m = -3e38
    if (__any(tmax > m + 8.f)) {
      float mn = fmaxf(m, tmax);
      float sf = exp2v(m - mn);
      lsum *= sf;
      m = mn;
      int lb = lane & 48;
      float sfr[4];
#pragma unroll
      for (int r = 0; r < 4; r++) sfr[r] = __shfl(sf, lb + g * 4 + r);
#pragma unroll
      for (int dt = 0; dt < 4; dt++)
#pragma unroll
        for (int r = 0; r < 4; r++) acc[dt][r] *= sfr[r];
    }

    // ---- p = exp2(s - m); pack to bf16; 4x ds_write_b64 (swizzled)
    float ps = 0.f;
#pragma unroll
    for (int ks = 0; ks < 4; ks++) {
      float p0 = exp2v(s[ks][0] - m);
      float p1 = exp2v(s[ks][1] - m);
      float p2 = exp2v(s[ks][2] - m);
      float p3 = exp2v(s[ks][3] - m);
      ps += (p0 + p1) + (p2 + p3);
      *(int2*)pw[ks] = make_int2((int)cvtpk(p0, p1), (int)cvtpk(p2, p3));
    }
    lsum += ps;   // per-lane partial (its own 16 k's); reduced after the loop

    // cross-lane LDS RAW (P written by other lanes of this wave): drain LDS
    asm volatile("s_waitcnt lgkmcnt(0)" ::: "memory");

    // ---- O += P V (P as A-operand, V^T tile from LDS as B-operand)
    short8 ap0 = *(const short8*)pr0;
    short8 ap1 = *(const short8*)pr1;
    int vb_l = 16384 + buf * 8192 + kfrag;
    __builtin_amdgcn_s_setprio(1);
#pragma unroll
    for (int dt = 0; dt < 4; dt++) {
      short8 v0 = *(const short8*)(smem + (vb_l + dt * 2048));
      short8 v1 = *(const short8*)(smem + ((vb_l + dt * 2048) ^ 64));
      acc[dt] = __builtin_amdgcn_mfma_f32_16x16x32_bf16(ap0, v0, acc[dt], 0, 0, 0);
      acc[dt] = __builtin_amdgcn_mfma_f32_16x16x32_bf16(ap1, v1, acc[dt], 0, 0, 0);
    }
    __builtin_amdgcn_s_setprio(0);

    __syncthreads();   // drains vmcnt(0): next tile staged; cur reads done
  }

  // ---- epilogue: reduce lsum across g-groups, redistribute 1/l to q-rows
  lsum += __shfl_xor(lsum, 16);
  lsum += __shfl_xor(lsum, 32);
  float linv = lsum > 0.f ? 1.f / lsum : 0.f;
  int lb = lane & 48;
  float li[4];
#pragma unroll
  for (int r = 0; r < 4; r++) li[r] = __shfl(linv, lb + g * 4 + r);

#pragma unroll
  for (int r = 0; r < 4; r++) {
    int q = qt * 64 + w * 16 + g * 4 + r;
#pragma unroll
    for (int dt = 0; dt < 4; dt++)
      aout[((size_t)(n * LSEQ + q)) * EMB + h * HD + dt * 16 + q0] =
          bf16r(acc[dt][r] * li[r]);
  }
}

// --------------------------------------------------- final projection + bias
__global__ __launch_bounds__(256) void outproj_kernel(
    const short* __restrict__ aout, const short* __restrict__ Wob,
    const float* __restrict__ bo, float* __restrict__ out) {
  int mt = blockIdx.x, nt = blockIdx.y;
  int tid = threadIdx.x, lane = tid & 63, w = tid >> 6;
  int row16 = lane & 15, g = lane >> 4;
  int mrow = mt * 64 + w * 16;

  f32x4 acc[4];
#pragma unroll
  for (int et = 0; et < 4; et++) acc[et] = (f32x4){0.f, 0.f, 0.f, 0.f};

  for (int kc = 0; kc < 16; kc++) {
    short8 a = ld8(aout + (size_t)(mrow + row16) * EMB + kc * 32 + g * 8);
#pragma unroll
    for (int et = 0; et < 4; et++) {
      short8 b = ld8(Wob + (size_t)(nt * 64 + et * 16 + row16) * EMB + kc * 32 + g * 8);
      acc[et] = __builtin_amdgcn_mfma_f32_16x16x32_bf16(a, b, acc[et], 0, 0, 0);
    }
  }
#pragma unroll
  for (int et = 0; et < 4; et++) {
    int e = nt * 64 + et * 16 + row16;
    float bias = bo[e];
#pragma unroll
    for (int r = 0; r < 4; r++) {
      int row = mrow + g * 4 + r;
      out[(size_t)row * EMB + e] = acc[et][r] + bias;
    }
  }
}

extern "C" void kernel_launch(void* const* d_in, const int* in_sizes, int n_in,
                              void* d_out, int out_size, void* d_ws, size_t ws_size,
                              hipStream_t stream) {
  const float* values = (const float*)d_in[0];
  const float* keys   = (const float*)d_in[1];
  const float* query  = (const float*)d_in[2];
  const int*   mask   = (const int*)d_in[3];
  const float* Wv     = (const float*)d_in[4];
  const float* Wk     = (const float*)d_in[5];
  const float* Wq     = (const float*)d_in[6];
  const float* Wo     = (const float*)d_in[7];
  const float* bo     = (const float*)d_in[8];
  float* out = (float*)d_out;

  // Qp/Kp scratch in d_out (16 MB, overwritten by outproj last; stream-ordered)
  short* Qp = (short*)d_out;
  short* Kp = (short*)((char*)d_out + (8u << 20));
  char* ws = (char*)d_ws;
  short* Vt    = (short*)(ws);                            //  8 MB
  short* aout  = (short*)(ws + (8u << 20));               //  8 MB
  short* Wob   = (short*)(ws + (16u << 20));              // 0.5 MB
  float* fbias = (float*)(ws + (16u << 20) + (512u << 10)); // 32 KB

  cvt_wo<<<256, 256, 0, stream>>>(Wo, Wob);
  mask2bias<<<32, 256, 0, stream>>>(mask, fbias);
  proj_kernel<<<dim3(NBATCH * NH * (LSEQ / 64), 3), 256, 0, stream>>>(
      query, keys, values, Wq, Wk, Wv, Qp, Kp, Vt);
  attn_kernel<<<NBATCH * NH * (LSEQ / 64), 256, 0, stream>>>(Qp, Kp, Vt, fbias, aout);
  outproj_kernel<<<dim3((NBATCH * LSEQ) / 64, EMB / 64), 256, 0, stream>>>(
      aout, Wob, bo, out);
}

// Round 8
// 134.012 us; speedup vs baseline: 2.4358x; 1.0573x over previous
//
#include <hip/hip_runtime.h>

#define LSEQ 2048
#define EMB  512
#define NH   8
#define HD   64
#define NBATCH 4
// 1/sqrt(512) * log2(e): folded into Q projection; softmax runs in exp2 domain
#define QSCALE (0.044194173824159216f * 1.4426950408889634f)

using short8  = __attribute__((ext_vector_type(8))) short;
using short4v = __attribute__((ext_vector_type(4))) short;
using f32x4   = __attribute__((ext_vector_type(4))) float;

__device__ __forceinline__ short bf16r(float f) {
  union { float f; unsigned u; } x; x.f = f;
  unsigned r = x.u + 0x7FFFu + ((x.u >> 16) & 1u);
  return (short)(r >> 16);
}

__device__ __forceinline__ float exp2v(float x) {
  float r;
  asm("v_exp_f32 %0, %1" : "=v"(r) : "v"(x));   // D = 2^S0
  return r;
}

// pack two f32 -> two bf16 in one dword (lo -> [15:0], hi -> [31:16])
__device__ __forceinline__ unsigned cvtpk(float lo, float hi) {
  unsigned r;
  asm("v_cvt_pk_bf16_f32 %0, %1, %2" : "=v"(r) : "v"(lo), "v"(hi));
  return r;
}

// async global->LDS, 16B per lane; lds dest is wave-uniform (HW adds lane*16)
__device__ __forceinline__ void stage16(const void* g, void* l) {
  __builtin_amdgcn_global_load_lds(
      (const __attribute__((address_space(1))) unsigned int*)g,
      (__attribute__((address_space(3))) unsigned int*)l, 16, 0, 0);
}

__device__ __forceinline__ short8 cvt8(const float* __restrict__ p) {
  float4 a = ((const float4*)p)[0];
  float4 b = ((const float4*)p)[1];
  short8 r;
  r[0]=bf16r(a.x); r[1]=bf16r(a.y); r[2]=bf16r(a.z); r[3]=bf16r(a.w);
  r[4]=bf16r(b.x); r[5]=bf16r(b.y); r[6]=bf16r(b.z); r[7]=bf16r(b.w);
  return r;
}

__device__ __forceinline__ short8 ld8(const short* __restrict__ p) {
  return *(const short8*)p;
}

// --------------------------- prep: Wo -> bf16 AND mask -> additive f32 bias
__global__ __launch_bounds__(256) void prep_kernel(
    const float* __restrict__ Wo, short* __restrict__ Wob,
    const int* __restrict__ mask, float* __restrict__ fbias) {
  int b = blockIdx.x;
  if (b < 256) {
    int i = b * 256 + threadIdx.x;
    float4 v = ((const float4*)Wo)[i];
    short4v r;
    r[0]=bf16r(v.x); r[1]=bf16r(v.y); r[2]=bf16r(v.z); r[3]=bf16r(v.w);
    ((short4v*)Wob)[i] = r;
  } else {
    int i = (b - 256) * 256 + threadIdx.x;    // 32 blocks * 256 = 8192
    fbias[i] = mask[i] ? 0.f : -1e30f;
  }
}

// ------------------------------------------------- per-head QKV projections
// Output tile staged in LDS, then written as coalesced 128B rows (fixes the
// 2B-scattered Vt transpose stores: 64 cache lines per inst -> 8 segments).
__global__ __launch_bounds__(256) void proj_kernel(
    const float* __restrict__ query, const float* __restrict__ keys,
    const float* __restrict__ values,
    const float* __restrict__ Wq, const float* __restrict__ Wk,
    const float* __restrict__ Wv,
    short* __restrict__ Qp, short* __restrict__ Kp, short* __restrict__ Vt) {
  __shared__ short tile[64][72];                 // +8 pad
  int t = blockIdx.y;
  const float* x = (t == 0) ? query : (t == 1) ? keys : values;
  const float* W = (t == 0) ? Wq    : (t == 1) ? Wk   : Wv;
  int idx = blockIdx.x;
  int lt = idx & 31, h = (idx >> 5) & 7, n = idx >> 8;
  int tid = threadIdx.x, lane = tid & 63, w = tid >> 6;
  int row16 = lane & 15, g = lane >> 4;
  int lbase = lt * 64 + w * 16;

  const float* xr = x + ((size_t)(n * LSEQ + lbase + row16)) * EMB + h * HD + g * 8;
  short8 a0 = cvt8(xr);
  short8 a1 = cvt8(xr + 32);

  f32x4 acc[4];
#pragma unroll
  for (int et = 0; et < 4; et++) acc[et] = (f32x4){0.f, 0.f, 0.f, 0.f};
#pragma unroll
  for (int et = 0; et < 4; et++) {
    const float* wr = W + (size_t)(et * 16 + row16) * HD + g * 8;
    short8 b0 = cvt8(wr);
    short8 b1 = cvt8(wr + 32);
    acc[et] = __builtin_amdgcn_mfma_f32_16x16x32_bf16(a0, b0, acc[et], 0, 0, 0);
    acc[et] = __builtin_amdgcn_mfma_f32_16x16x32_bf16(a1, b1, acc[et], 0, 0, 0);
  }

  float sc = (t == 0) ? QSCALE : 1.f;
  // stage to LDS: Q/K as [l][e]; V transposed as [d][l]
  if (t == 2) {
#pragma unroll
    for (int et = 0; et < 4; et++)
#pragma unroll
      for (int r = 0; r < 4; r++)
        tile[et * 16 + row16][w * 16 + g * 4 + r] = bf16r(acc[et][r]);
  } else {
#pragma unroll
    for (int et = 0; et < 4; et++)
#pragma unroll
      for (int r = 0; r < 4; r++)
        tile[w * 16 + g * 4 + r][et * 16 + row16] = bf16r(acc[et][r] * sc);
  }
  __syncthreads();

  size_t nh = (size_t)(n * NH + h);
  // coalesced write: 64 rows x 128B (8 chunks of 16B per row)
#pragma unroll
  for (int i = tid; i < 512; i += 256) {
    int rr = i >> 3, cc = i & 7;
    short8 v = *(const short8*)&tile[rr][cc * 8];
    if (t == 2)
      *(short8*)(Vt + (nh * HD + rr) * LSEQ + lt * 64 + cc * 8) = v;
    else {
      short* O = (t == 0) ? Qp : Kp;
      *(short8*)(O + (nh * LSEQ + lt * 64 + rr) * HD + cc * 8) = v;
    }
  }
}

// ------------------------------------------------------------ flash attention
// block = (n, h, qtile of 128); 4 waves x 32 q-rows (two 16-row halves) share
// the 64-key K/V LDS tile -> every K/V fragment read feeds 2x MFMA (halves
// the LDS-read bytes per FLOP, the round-7 bottleneck). Async double-buffered
// staging, chunk-XOR swizzle, swapped QK^T (softmax in-lane, exp2 domain),
// mask bias folded into MFMA C-init. XCD-bijective blockIdx swizzle keeps all
// 16 q-blocks of one (n,h) on one XCD (K/V 2MB < 4MB L2).
// LDS: K0 K1 V0 V1 (4x8K) + P 4 waves x 4K = 49152 B.
__global__ __launch_bounds__(256, 2) void attn_kernel(
    const short* __restrict__ Qp, const short* __restrict__ Kp,
    const short* __restrict__ Vt, const float* __restrict__ fbias,
    short* __restrict__ aout) {
  __shared__ __align__(16) char smem[49152];

  int idx = blockIdx.x;
  // idx = (n)*128 + qt*8 + h  -> XCD (idx%8) == h; 4 n-groups per XCD
  int h = idx & 7;
  int qt = (idx >> 3) & 15;
  int n = idx >> 7;
  int tid = threadIdx.x, lane = tid & 63, w = tid >> 6;
  int q0 = lane & 15, g = lane >> 4;
  int xr = q0 & 7;

  size_t nh = (size_t)(n * NH + h);
  const short* Qb = Qp + (nh * LSEQ + qt * 128 + w * 32) * HD;
  short8 bq00 = ld8(Qb + q0 * HD + g * 8);          // half 0
  short8 bq01 = ld8(Qb + q0 * HD + 32 + g * 8);
  short8 bq10 = ld8(Qb + (16 + q0) * HD + g * 8);   // half 1
  short8 bq11 = ld8(Qb + (16 + q0) * HD + 32 + g * 8);

  f32x4 acc0[4], acc1[4];
#pragma unroll
  for (int dt = 0; dt < 4; dt++) {
    acc0[dt] = (f32x4){0.f, 0.f, 0.f, 0.f};
    acc1[dt] = (f32x4){0.f, 0.f, 0.f, 0.f};
  }
  float m0 = -3e38f, l0 = 0.f, m1 = -3e38f, l1 = 0.f;

  const char* Ksrc = (const char*)(Kp + nh * (size_t)LSEQ * HD);  // [l][d] 128B rows
  const char* Vsrc = (const char*)(Vt + nh * (size_t)HD * LSEQ);  // [d][L] 4KB rows
  const float* fb  = fbias + n * LSEQ + g * 4;

  // staging: K/V tile = 64 rows x 128B = 512 x 16B chunks; source col ^= row&7
  int c0 = w * 64 + lane, r0 = c0 >> 3, col0 = (c0 & 7) ^ (r0 & 7);
  int c1 = c0 + 256,      r1 = c1 >> 3, col1 = (c1 & 7) ^ (r1 & 7);
  int ksoff0 = r0 * 128 + col0 * 16;
  int ksoff1 = r1 * 128 + col1 * 16;
  int vsoff0 = r0 * (LSEQ * 2) + col0 * 16;
  int vsoff1 = r1 * (LSEQ * 2) + col1 * 16;
  int ldoff0 = (w * 64) * 16;
  int ldoff1 = ldoff0 + 256 * 16;

  // swizzled K/V read offset within a tile
  int kfrag = q0 * 128 + ((g ^ xr) << 4);          // + ks*2048; K=32 half1 = ^64
  // P region: per wave 32 rows x 128B; half1 = +2048 (folds into ds imm)
  int pbase = 32768 + w * 4096 + q0 * 128;
  char* pw[4];
#pragma unroll
  for (int ks = 0; ks < 4; ks++)
    pw[ks] = smem + pbase + ((ks * 32 + g * 8) ^ (xr << 4));
  const char* pr0 = smem + pbase + ((g * 16) ^ (xr << 4));
  const char* pr1 = smem + pbase + ((64 + g * 16) ^ (xr << 4));

  // prologue: stage k-tile 0 into buf0
  stage16(Ksrc + ksoff0, smem + ldoff0);
  stage16(Ksrc + ksoff1, smem + ldoff1);
  stage16(Vsrc + vsoff0, smem + 16384 + ldoff0);
  stage16(Vsrc + vsoff1, smem + 16384 + ldoff1);
  __syncthreads();

  for (int kt = 0; kt < 32; kt++) {
    int buf = kt & 1;
    if (kt < 31) {
      int nkb = (kt + 1) * 64;
      int bo = (buf ^ 1) * 8192;
      stage16(Ksrc + nkb * 128 + ksoff0, smem + bo + ldoff0);
      stage16(Ksrc + nkb * 128 + ksoff1, smem + bo + ldoff1);
      stage16(Vsrc + nkb * 2 + vsoff0, smem + 16384 + bo + ldoff0);
      stage16(Vsrc + nkb * 2 + vsoff1, smem + 16384 + bo + ldoff1);
    }
    f32x4 fbv[4];
#pragma unroll
    for (int ks = 0; ks < 4; ks++)
      fbv[ks] = *(const f32x4*)(fb + kt * 64 + ks * 16);

    // ---- S^T = K Q^T for both q-halves; bias pre-loaded as MFMA C-init
    int kb_l = buf * 8192 + kfrag;
    f32x4 s0[4], s1[4];
    __builtin_amdgcn_s_setprio(1);
#pragma unroll
    for (int ks = 0; ks < 4; ks++) {
      short8 k0 = *(const short8*)(smem + (kb_l + ks * 2048));
      short8 k1 = *(const short8*)(smem + ((kb_l + ks * 2048) ^ 64));
      f32x4 t0 = __builtin_amdgcn_mfma_f32_16x16x32_bf16(k0, bq00, fbv[ks], 0, 0, 0);
      s0[ks]   = __builtin_amdgcn_mfma_f32_16x16x32_bf16(k1, bq01, t0, 0, 0, 0);
      f32x4 t1 = __builtin_amdgcn_mfma_f32_16x16x32_bf16(k0, bq10, fbv[ks], 0, 0, 0);
      s1[ks]   = __builtin_amdgcn_mfma_f32_16x16x32_bf16(k1, bq11, t1, 0, 0, 0);
    }
    __builtin_amdgcn_s_setprio(0);

    // ---- per-half row max (in-lane 16 + xor16/xor32)
    float a0 = fmaxf(fmaxf(s0[0][0], s0[0][1]), s0[0][2]);
    float a1 = fmaxf(fmaxf(s0[0][3], s0[1][0]), s0[1][1]);
    float a2 = fmaxf(fmaxf(s0[1][2], s0[1][3]), s0[2][0]);
    float a3 = fmaxf(fmaxf(s0[2][1], s0[2][2]), s0[2][3]);
    float a4 = fmaxf(fmaxf(s0[3][0], s0[3][1]), s0[3][2]);
    float tmax0 = fmaxf(fmaxf(fmaxf(a0, a1), fmaxf(a2, a3)), fmaxf(a4, s0[3][3]));
    float b0 = fmaxf(fmaxf(s1[0][0], s1[0][1]), s1[0][2]);
    float b1 = fmaxf(fmaxf(s1[0][3], s1[1][0]), s1[1][1]);
    float b2 = fmaxf(fmaxf(s1[1][2], s1[1][3]), s1[2][0]);
    float b3 = fmaxf(fmaxf(s1[2][1], s1[2][2]), s1[2][3]);
    float b4 = fmaxf(fmaxf(s1[3][0], s1[3][1]), s1[3][2]);
    float tmax1 = fmaxf(fmaxf(fmaxf(b0, b1), fmaxf(b2, b3)), fmaxf(b4, s1[3][3]));
    tmax0 = fmaxf(tmax0, __shfl_xor(tmax0, 16));
    tmax0 = fmaxf(tmax0, __shfl_xor(tmax0, 32));
    tmax1 = fmaxf(tmax1, __shfl_xor(tmax1, 16));
    tmax1 = fmaxf(tmax1, __shfl_xor(tmax1, 32));

    // ---- defer-max rescale (T13)
    int grew = (tmax0 > m0 + 8.f) | (tmax1 > m1 + 8.f);
    if (__any(grew)) {
      int lb = lane & 48;
      float mn0 = fmaxf(m0, tmax0), sf0 = exp2v(m0 - mn0);
      l0 *= sf0; m0 = mn0;
      float mn1 = fmaxf(m1, tmax1), sf1 = exp2v(m1 - mn1);
      l1 *= sf1; m1 = mn1;
      float s0r[4], s1r[4];
#pragma unroll
      for (int r = 0; r < 4; r++) {
        s0r[r] = __shfl(sf0, lb + g * 4 + r);
        s1r[r] = __shfl(sf1, lb + g * 4 + r);
      }
#pragma unroll
      for (int dt = 0; dt < 4; dt++)
#pragma unroll
        for (int r = 0; r < 4; r++) {
          acc0[dt][r] *= s0r[r];
          acc1[dt][r] *= s1r[r];
        }
    }

    // ---- p = exp2(s - m), pack, write P (half0 at +0, half1 at +2048)
    float ps0 = 0.f, ps1 = 0.f;
#pragma unroll
    for (int ks = 0; ks < 4; ks++) {
      float p0 = exp2v(s0[ks][0] - m0), p1 = exp2v(s0[ks][1] - m0);
      float p2 = exp2v(s0[ks][2] - m0), p3 = exp2v(s0[ks][3] - m0);
      ps0 += (p0 + p1) + (p2 + p3);
      *(int2*)pw[ks] = make_int2((int)cvtpk(p0, p1), (int)cvtpk(p2, p3));
      float q1 = exp2v(s1[ks][0] - m1), q2 = exp2v(s1[ks][1] - m1);
      float q3 = exp2v(s1[ks][2] - m1), q4 = exp2v(s1[ks][3] - m1);
      ps1 += (q1 + q2) + (q3 + q4);
      *(int2*)(pw[ks] + 2048) = make_int2((int)cvtpk(q1, q2), (int)cvtpk(q3, q4));
    }
    l0 += ps0; l1 += ps1;

    asm volatile("s_waitcnt lgkmcnt(0)" ::: "memory");

    // ---- O += P V (V fragments shared by both halves)
    short8 ap00 = *(const short8*)pr0;
    short8 ap01 = *(const short8*)pr1;
    short8 ap10 = *(const short8*)(pr0 + 2048);
    short8 ap11 = *(const short8*)(pr1 + 2048);
    int vb_l = 16384 + buf * 8192 + kfrag;
    __builtin_amdgcn_s_setprio(1);
#pragma unroll
    for (int dt = 0; dt < 4; dt++) {
      short8 v0 = *(const short8*)(smem + (vb_l + dt * 2048));
      short8 v1 = *(const short8*)(smem + ((vb_l + dt * 2048) ^ 64));
      acc0[dt] = __builtin_amdgcn_mfma_f32_16x16x32_bf16(ap00, v0, acc0[dt], 0, 0, 0);
      acc0[dt] = __builtin_amdgcn_mfma_f32_16x16x32_bf16(ap01, v1, acc0[dt], 0, 0, 0);
      acc1[dt] = __builtin_amdgcn_mfma_f32_16x16x32_bf16(ap10, v0, acc1[dt], 0, 0, 0);
      acc1[dt] = __builtin_amdgcn_mfma_f32_16x16x32_bf16(ap11, v1, acc1[dt], 0, 0, 0);
    }
    __builtin_amdgcn_s_setprio(0);

    __syncthreads();   // vmcnt(0) drain: next tile staged; cur LDS reads done
  }

  // ---- epilogue
  l0 += __shfl_xor(l0, 16);  l0 += __shfl_xor(l0, 32);
  l1 += __shfl_xor(l1, 16);  l1 += __shfl_xor(l1, 32);
  float li0 = l0 > 0.f ? 1.f / l0 : 0.f;
  float li1 = l1 > 0.f ? 1.f / l1 : 0.f;
  int lb = lane & 48;
  float w0[4], w1[4];
#pragma unroll
  for (int r = 0; r < 4; r++) {
    w0[r] = __shfl(li0, lb + g * 4 + r);
    w1[r] = __shfl(li1, lb + g * 4 + r);
  }
  int qrow = qt * 128 + w * 32;
#pragma unroll
  for (int r = 0; r < 4; r++) {
    size_t o0 = ((size_t)(n * LSEQ + qrow + g * 4 + r)) * EMB + h * HD;
    size_t o1 = ((size_t)(n * LSEQ + qrow + 16 + g * 4 + r)) * EMB + h * HD;
#pragma unroll
    for (int dt = 0; dt < 4; dt++) {
      aout[o0 + dt * 16 + q0] = bf16r(acc0[dt][r] * w0[r]);
      aout[o1 + dt * 16 + q0] = bf16r(acc1[dt][r] * w1[r]);
    }
  }
}

// --------------------------------------------------- final projection + bias
__global__ __launch_bounds__(256) void outproj_kernel(
    const short* __restrict__ aout, const short* __restrict__ Wob,
    const float* __restrict__ bo, float* __restrict__ out) {
  int mt = blockIdx.x, nt = blockIdx.y;
  int tid = threadIdx.x, lane = tid & 63, w = tid >> 6;
  int row16 = lane & 15, g = lane >> 4;
  int mrow = mt * 64 + w * 16;

  f32x4 acc[4];
#pragma unroll
  for (int et = 0; et < 4; et++) acc[et] = (f32x4){0.f, 0.f, 0.f, 0.f};

  for (int kc = 0; kc < 16; kc++) {
    short8 a = ld8(aout + (size_t)(mrow + row16) * EMB + kc * 32 + g * 8);
#pragma unroll
    for (int et = 0; et < 4; et++) {
      short8 b = ld8(Wob + (size_t)(nt * 64 + et * 16 + row16) * EMB + kc * 32 + g * 8);
      acc[et] = __builtin_amdgcn_mfma_f32_16x16x32_bf16(a, b, acc[et], 0, 0, 0);
    }
  }
#pragma unroll
  for (int et = 0; et < 4; et++) {
    int e = nt * 64 + et * 16 + row16;
    float bias = bo[e];
#pragma unroll
    for (int r = 0; r < 4; r++) {
      int row = mrow + g * 4 + r;
      out[(size_t)row * EMB + e] = acc[et][r] + bias;
    }
  }
}

extern "C" void kernel_launch(void* const* d_in, const int* in_sizes, int n_in,
                              void* d_out, int out_size, void* d_ws, size_t ws_size,
                              hipStream_t stream) {
  const float* values = (const float*)d_in[0];
  const float* keys   = (const float*)d_in[1];
  const float* query  = (const float*)d_in[2];
  const int*   mask   = (const int*)d_in[3];
  const float* Wv     = (const float*)d_in[4];
  const float* Wk     = (const float*)d_in[5];
  const float* Wq     = (const float*)d_in[6];
  const float* Wo     = (const float*)d_in[7];
  const float* bo     = (const float*)d_in[8];
  float* out = (float*)d_out;

  // Qp/Kp scratch in d_out (16 MB, overwritten by outproj last; stream-ordered)
  short* Qp = (short*)d_out;
  short* Kp = (short*)((char*)d_out + (8u << 20));
  char* ws = (char*)d_ws;
  short* Vt    = (short*)(ws);                            //  8 MB
  short* aout  = (short*)(ws + (8u << 20));               //  8 MB
  short* Wob   = (short*)(ws + (16u << 20));              // 0.5 MB
  float* fbias = (float*)(ws + (16u << 20) + (512u << 10)); // 32 KB

  prep_kernel<<<288, 256, 0, stream>>>(Wo, Wob, mask, fbias);
  proj_kernel<<<dim3(NBATCH * NH * (LSEQ / 64), 3), 256, 0, stream>>>(
      query, keys, values, Wq, Wk, Wv, Qp, Kp, Vt);
  attn_kernel<<<NBATCH * NH * (LSEQ / 128), 256, 0, stream>>>(Qp, Kp, Vt, fbias, aout);
  outproj_kernel<<<dim3((NBATCH * LSEQ) / 64, EMB / 64), 256, 0, stream>>>(
      aout, Wob, bo, out);
}